// Round 13
// baseline (242.252 us; speedup 1.0000x reference)
//
#include <hip/hip_runtime.h>
#include <hip/hip_bf16.h>

typedef __bf16 bf16_t;
typedef __bf16 bf16x4 __attribute__((ext_vector_type(4)));
typedef __bf16 bf16x8 __attribute__((ext_vector_type(8)));
typedef float f32x4 __attribute__((ext_vector_type(4)));

#define AS1(p) ((const __attribute__((address_space(1))) void*)(p))
#define AS3(p) ((__attribute__((address_space(3))) void*)(p))

__device__ __forceinline__ f32x4 mfma16(bf16x8 a, bf16x8 b, f32x4 c) {
  return __builtin_amdgcn_mfma_f32_16x16x32_bf16(a, b, c, 0, 0, 0);
}

// ---- fused prep: x cast + 4 weight transposes + combined bias build ----
__global__ void prep(const float* __restrict__ x, const float* __restrict__ Wq,
                     const float* __restrict__ Wk, const float* __restrict__ Wv,
                     const float* __restrict__ Wo, const float* __restrict__ bq,
                     const float* __restrict__ bk, const float* __restrict__ bv,
                     bf16_t* __restrict__ xb, bf16_t* __restrict__ WqT,
                     bf16_t* __restrict__ WkvT, bf16_t* __restrict__ WoT,
                     float* __restrict__ bqkv) {
  const int u = blockIdx.x;
  if (u >= 546) {  // x cast: 8192*1024 f32 -> bf16, 4/lane
    int i = ((u - 546) * 256 + threadIdx.x) * 4;
    float4 v = *(const float4*)(x + i);
    bf16x4 o = {(bf16_t)v.x, (bf16_t)v.y, (bf16_t)v.z, (bf16_t)v.w};
    *(bf16x4*)(xb + i) = o;
    return;
  }
  if (u == 544) {  // bq copy (1024 f32)
    int i = threadIdx.x * 4;
    *(float4*)(bqkv + i) = *(const float4*)(bq + i);
    return;
  }
  if (u == 545) {  // bk/bv pack
    if (threadIdx.x < 128)
      bqkv[1024 + threadIdx.x] =
          (threadIdx.x < 64) ? bk[threadIdx.x] : bv[threadIdx.x - 64];
    return;
  }
  const float* W; bf16_t* Wt; int N, bx, by;
  if (u < 256)      { W = Wq; Wt = WqT;              N = 1024; bx = u & 15;         by = u >> 4; }
  else if (u < 272) { W = Wk; Wt = WkvT;             N = 64;   bx = 0;              by = u - 256; }
  else if (u < 288) { W = Wv; Wt = WkvT + 64 * 1024; N = 64;   bx = 0;              by = u - 272; }
  else              { W = Wo; Wt = WoT;              N = 1024; bx = (u - 288) & 15; by = (u - 288) >> 4; }
  __shared__ float t[64][65];
  const int n0 = bx * 64, k0 = by * 64;
  const int tx = threadIdx.x & 63, ty = threadIdx.x >> 6;
#pragma unroll
  for (int i = 0; i < 16; ++i)
    t[ty * 16 + i][tx] = W[(size_t)(k0 + ty * 16 + i) * N + n0 + tx];
  __syncthreads();
#pragma unroll
  for (int i = 0; i < 16; ++i)
    Wt[(size_t)(n0 + ty * 16 + i) * 1024 + k0 + tx] = (bf16_t)t[tx][ty * 16 + i];
}

// Fused Q+KV projection, BM=64 x BN=128, BK=32, dbuf (1 barrier/iter).
// Round-11 post-mortem: the 2-barrier schedule is closed (dbuf neutral, BK=64
// worse). Remaining qkv inefficiency is DISPATCH PACKING: 576 equal blocks at
// 2-deep residency -> 512 concurrent -> the 64-block tail runs a near-idle
// round (~25% of qkv time). BM=64 -> 1152 blocks pack 4.5-deep (ceil loss
// ~11%) AND doubles waves/SIMD to 4.5 (acc 32 regs/wave, VGPR ~80).
// Wave w owns cols w*32..w*32+31; all waves share the A rows (LDS broadcast).
__global__ __launch_bounds__(256, 2)
void gemm_qkv(const bf16_t* __restrict__ A, const bf16_t* __restrict__ Bt,
              const float* __restrict__ bias, bf16_t* __restrict__ Qb,
              bf16_t* __restrict__ KVb, bf16_t* __restrict__ VtG, int M, int K) {
  __shared__ __align__(16) bf16_t As[2][64 * 32];
  __shared__ __align__(16) bf16_t Bs[2][128 * 32];
  const int tid = threadIdx.x;
  const int w = tid >> 6, l = tid & 63;
  const int l15 = l & 15, q = l >> 4;
  const int m0 = blockIdx.x * 64, n0 = blockIdx.y * 128;
  f32x4 acc[4][2] = {};
  // A staging: chunk cA = w*64+l -> row cA>>2, 16B kchunk cA&3 (1 instr/wave)
  const int cA = w * 64 + l;
  const int rAr = m0 + (cA >> 2), kA = (cA & 3) * 8;
  // B staging: chunks (i*4+w)*64+l, i=0,1 (2 instr/wave)
  int rBr[2], kB[2], cB[2];
#pragma unroll
  for (int i = 0; i < 2; ++i) {
    cB[i] = (i * 4 + w) * 64 + l;
    rBr[i] = n0 + (cB[i] >> 2);
    kB[i] = (cB[i] & 3) * 8;
  }
  // prologue: stage tile 0 into buffer 0
  __builtin_amdgcn_global_load_lds(AS1(A + (size_t)rAr * K + kA),
                                   AS3(&As[0][0] + cA * 8), 16, 0, 0);
#pragma unroll
  for (int i = 0; i < 2; ++i)
    __builtin_amdgcn_global_load_lds(AS1(Bt + (size_t)rBr[i] * K + kB[i]),
                                     AS3(&Bs[0][0] + cB[i] * 8), 16, 0, 0);
  const int NT = K / 32;
  for (int t = 0; t < NT; ++t) {
    __syncthreads();  // drains stage(t); releases the other buffer
    const int cur = t & 1;
    if (t + 1 < NT) {
      const int k0n = (t + 1) * 32;
      __builtin_amdgcn_global_load_lds(AS1(A + (size_t)rAr * K + k0n + kA),
                                       AS3(&As[cur ^ 1][0] + cA * 8), 16, 0, 0);
#pragma unroll
      for (int i = 0; i < 2; ++i)
        __builtin_amdgcn_global_load_lds(AS1(Bt + (size_t)rBr[i] * K + k0n + kB[i]),
                                         AS3(&Bs[cur ^ 1][0] + cB[i] * 8), 16, 0, 0);
    }
    bf16x8 af[4], bfr[2];
#pragma unroll
    for (int mi = 0; mi < 4; ++mi)
      af[mi] = *(const bf16x8*)(&As[cur][0] + (mi * 16 + l15) * 32 + q * 8);
#pragma unroll
    for (int ni = 0; ni < 2; ++ni)
      bfr[ni] = *(const bf16x8*)(&Bs[cur][0] + (w * 32 + ni * 16 + l15) * 32 + q * 8);
#pragma unroll
    for (int mi = 0; mi < 4; ++mi)
#pragma unroll
      for (int ni = 0; ni < 2; ++ni)
        acc[mi][ni] = mfma16(af[mi], bfr[ni], acc[mi][ni]);
  }
#pragma unroll
  for (int ni = 0; ni < 2; ++ni) {
    int col = n0 + w * 32 + ni * 16 + l15;
    float bv = bias[col];
#pragma unroll
    for (int mi = 0; mi < 4; ++mi)
#pragma unroll
      for (int r = 0; r < 4; ++r) {
        int row = m0 + mi * 16 + q * 4 + r;
        bf16_t v = (bf16_t)(acc[mi][ni][r] + bv);
        if (col < 1024) {
          Qb[(size_t)row * 1024 + col] = v;
        } else {
          int c2 = col - 1024;
          KVb[(size_t)row * 128 + c2] = v;
          if (c2 >= 64)
            VtG[(size_t)((row >> 11) * 64 + (c2 - 64)) * 2048 + (row & 2047)] = v;
        }
      }
  }
}

// O-projection GEMM, BK=32 + dbuf, 128x128, M-fastest grid.
// 512 blocks = exactly 2.0 rounds -> no tail problem; keep as-is.
__global__ __launch_bounds__(256, 2)
void gemm_nt_bias_f32(const bf16_t* __restrict__ A, const bf16_t* __restrict__ Bt,
                      const float* __restrict__ bias, float* __restrict__ C,
                      int M, int N, int K) {
  __shared__ __align__(16) bf16_t As[2][128 * 32];
  __shared__ __align__(16) bf16_t Bs[2][128 * 32];
  const int tid = threadIdx.x;
  const int w = tid >> 6, l = tid & 63;
  const int l15 = l & 15, q = l >> 4;
  const int m0 = blockIdx.x * 128, n0 = blockIdx.y * 128;
  const int mw = (w >> 1) * 64, nw = (w & 1) * 64;
  f32x4 acc[4][4] = {};
  const int kb = (l & 3) * 8;
  int rA[2], rB[2];
#pragma unroll
  for (int i = 0; i < 2; ++i) {
    int row = (i * 4 + w) * 16 + (l >> 2);
    rA[i] = m0 + row;
    int rb = n0 + row; if (rb >= N) rb = N - 1;
    rB[i] = rb;
  }
#pragma unroll
  for (int i = 0; i < 2; ++i) {
    int sg = i * 4 + w;
    __builtin_amdgcn_global_load_lds(AS1(A + (size_t)rA[i] * K + kb),
                                     AS3(&As[0][0] + sg * 512), 16, 0, 0);
    __builtin_amdgcn_global_load_lds(AS1(Bt + (size_t)rB[i] * K + kb),
                                     AS3(&Bs[0][0] + sg * 512), 16, 0, 0);
  }
  const int NT = K / 32;
  for (int t = 0; t < NT; ++t) {
    __syncthreads();
    const int cur = t & 1;
    if (t + 1 < NT) {
      const int k0n = (t + 1) * 32;
#pragma unroll
      for (int i = 0; i < 2; ++i) {
        int sg = i * 4 + w;
        __builtin_amdgcn_global_load_lds(AS1(A + (size_t)rA[i] * K + k0n + kb),
                                         AS3(&As[cur ^ 1][0] + sg * 512), 16, 0, 0);
        __builtin_amdgcn_global_load_lds(AS1(Bt + (size_t)rB[i] * K + k0n + kb),
                                         AS3(&Bs[cur ^ 1][0] + sg * 512), 16, 0, 0);
      }
    }
    bf16x8 af[4], bfr[4];
#pragma unroll
    for (int mi = 0; mi < 4; ++mi)
      af[mi] = *(const bf16x8*)(&As[cur][0] + (mw + mi * 16 + l15) * 32 + q * 8);
#pragma unroll
    for (int ni = 0; ni < 4; ++ni)
      bfr[ni] = *(const bf16x8*)(&Bs[cur][0] + (nw + ni * 16 + l15) * 32 + q * 8);
#pragma unroll
    for (int mi = 0; mi < 4; ++mi)
#pragma unroll
      for (int ni = 0; ni < 4; ++ni)
        acc[mi][ni] = mfma16(af[mi], bfr[ni], acc[mi][ni]);
  }
#pragma unroll
  for (int ni = 0; ni < 4; ++ni) {
    int col = n0 + nw + ni * 16 + l15;
    if (col >= N) continue;
    float bv = bias[col];
#pragma unroll
    for (int mi = 0; mi < 4; ++mi)
#pragma unroll
      for (int r = 0; r < 4; ++r) {
        int row = m0 + mw + mi * 16 + q * 4 + r;
        C[(size_t)row * N + col] = acc[mi][ni][r] + bv;
      }
  }
}

// ---- MQA flash v9 attn (proven 77.3us, VGPR 112, no spill) -- verbatim ----
__device__ __forceinline__ void load_q(const bf16_t* __restrict__ Qb, int b, int h,
                                       int qt, int l15, int q,
                                       bf16x8 (&qf0)[4], bf16x8 (&qf1)[4]) {
#pragma unroll
  for (int nq = 0; nq < 4; ++nq) {
    const bf16_t* qp = Qb + (size_t)(b * 2048 + qt * 64 + nq * 16 + l15) * 1024 + h * 64 + q * 8;
    qf0[nq] = *(const bf16x8*)qp;
    qf1[nq] = *(const bf16x8*)(qp + 32);
  }
}

template <bool DIAG>
__device__ __forceinline__ void attn_step(
    const bf16_t* __restrict__ kbase, const bf16_t* __restrict__ vbase, int kt,
    int l15, int q, bf16_t* __restrict__ ps,
    const bf16x8 (&qf0)[4], const bf16x8 (&qf1)[4],
    f32x4 (&o)[4][4], float (&rs)[4]) {
  const float c1 = 0.18033688f;  // log2(e)/8
  const bf16_t* kb = kbase + (size_t)kt * 64 * 128;  // K: cols 0-63 of KVb rows
  bf16x8 ka0[4], ka1[4];
#pragma unroll
  for (int mk = 0; mk < 4; ++mk) {
    const bf16_t* kr = kb + (mk * 16 + l15) * 128;
    ka0[mk] = *(const bf16x8*)(kr + q * 8);
    ka1[mk] = *(const bf16x8*)(kr + 32 + q * 8);
  }
  bf16x8 va0[4], va1[4];
#pragma unroll
  for (int md = 0; md < 4; ++md) {
    const bf16_t* vr = vbase + (size_t)(md * 16 + l15) * 2048 + kt * 64;
    va0[md] = *(const bf16x8*)(vr + q * 8);
    va1[md] = *(const bf16x8*)(vr + 32 + q * 8);
  }
  // S^T = K*Q^T in two mk-halves (bounds live s-registers)
#pragma unroll
  for (int mh = 0; mh < 2; ++mh) {
    f32x4 s2[2][4];
    __builtin_amdgcn_s_setprio(1);
#pragma unroll
    for (int mk2 = 0; mk2 < 2; ++mk2)
#pragma unroll
      for (int nq = 0; nq < 4; ++nq) {
        f32x4 t = {0.f, 0.f, 0.f, 0.f};
        t = mfma16(ka0[mh * 2 + mk2], qf0[nq], t);
        t = mfma16(ka1[mh * 2 + mk2], qf1[nq], t);
        s2[mk2][nq] = t;
      }
    __builtin_amdgcn_s_setprio(0);
#pragma unroll
    for (int nq = 0; nq < 4; ++nq)
#pragma unroll
      for (int mk2 = 0; mk2 < 2; ++mk2) {
        const int mk = mh * 2 + mk2;
        bf16x4 pk;
#pragma unroll
        for (int r = 0; r < 4; ++r) {
          float pv = __builtin_amdgcn_exp2f(s2[mk2][nq][r] * c1 - 16.0f);
          if (DIAG && (mk * 16 + q * 4 + r) > (nq * 16 + l15)) pv = 0.f;
          rs[nq] += pv;
          pk[r] = (bf16_t)pv;
        }
        *(bf16x4*)(ps + nq * 1152 + l15 * 72 + mk * 16 + q * 4) = pk;
      }
  }
  // O^T += V^T * P
#pragma unroll
  for (int nq = 0; nq < 4; ++nq) {
    bf16x8 pb0 = *(const bf16x8*)(ps + nq * 1152 + l15 * 72 + q * 8);
    bf16x8 pb1 = *(const bf16x8*)(ps + nq * 1152 + l15 * 72 + 32 + q * 8);
    __builtin_amdgcn_s_setprio(1);
#pragma unroll
    for (int md = 0; md < 4; ++md) {
      o[md][nq] = mfma16(va0[md], pb0, o[md][nq]);
      o[md][nq] = mfma16(va1[md], pb1, o[md][nq]);
    }
    __builtin_amdgcn_s_setprio(0);
  }
}

__device__ __forceinline__ void attn_finalize(bf16_t* __restrict__ AO, int b, int h,
                                              int qt, int l15, int q,
                                              f32x4 (&o)[4][4], float (&rs)[4]) {
#pragma unroll
  for (int nq = 0; nq < 4; ++nq) {
    rs[nq] += __shfl_xor(rs[nq], 16);
    rs[nq] += __shfl_xor(rs[nq], 32);
  }
  float inv[4];
#pragma unroll
  for (int nq = 0; nq < 4; ++nq) inv[nq] = 1.f / rs[nq];
#pragma unroll
  for (int md = 0; md < 4; ++md)
#pragma unroll
    for (int nq = 0; nq < 4; ++nq) {
      bf16x4 ov = {(bf16_t)(o[md][nq][0] * inv[nq]), (bf16_t)(o[md][nq][1] * inv[nq]),
                   (bf16_t)(o[md][nq][2] * inv[nq]), (bf16_t)(o[md][nq][3] * inv[nq])};
      *(bf16x4*)(AO + (size_t)(b * 2048 + qt * 64 + nq * 16 + l15) * 1024 +
                 h * 64 + md * 16 + q * 4) = ov;
    }
}

__global__ __launch_bounds__(128, 2)
void mqa_attn9(const bf16_t* __restrict__ Qb, const bf16_t* __restrict__ KVb,
               const bf16_t* __restrict__ VtG, bf16_t* __restrict__ AO) {
  __shared__ __align__(16) bf16_t Ps[2][4][16 * 72];  // 18 KB
  __shared__ __align__(16) float Oc[4096];            // 16 KB combine buffer
  __shared__ float RSc[256];                          // 1 KB
  const int u = blockIdx.x;
  const int b = u & 3;                 // one batch per XCD L2
  const int h = (u >> 2) & 15;
  const int p = (u >> 6) & 15;         // pair id; qt_h = 31-p, qt_l = p
  const int w = threadIdx.x >> 6, l = threadIdx.x & 63;
  const int l15 = l & 15, q = l >> 4;
  const int qt_h = 31 - p;
  bf16_t* ps = &Ps[w][0][0];
  const bf16_t* kbase = KVb + (size_t)b * 2048 * 128;
  const bf16_t* vbase = VtG + (size_t)b * 64 * 2048;

  bf16x8 qf0[4], qf1[4];
  f32x4 o[4][4] = {};
  float rs[4] = {0.f, 0.f, 0.f, 0.f};

  if (w == 0) {
    // first 17 steps of the heavy tile (diag included only when p==15)
    load_q(Qb, b, h, qt_h, l15, q, qf0, qf1);
    const int e = (p == 15) ? 16 : 17;
    for (int kt = 0; kt < e; ++kt)
      attn_step<false>(kbase, vbase, kt, l15, q, ps, qf0, qf1, o, rs);
    if (p == 15)
      attn_step<true>(kbase, vbase, 16, l15, q, ps, qf0, qf1, o, rs);
    __syncthreads();  // wave1's partial is in Oc/RSc
#pragma unroll
    for (int md = 0; md < 4; ++md)
#pragma unroll
      for (int nq = 0; nq < 4; ++nq)
        o[md][nq] += *(const f32x4*)&Oc[((md * 4 + nq) * 64 + l) * 4];
#pragma unroll
    for (int nq = 0; nq < 4; ++nq) rs[nq] += RSc[l * 4 + nq];
    attn_finalize(AO, b, h, qt_h, l15, q, o, rs);
  } else {
    // light tile complete (p steps + diag), written directly
    load_q(Qb, b, h, p, l15, q, qf0, qf1);
    for (int kt = 0; kt < p; ++kt)
      attn_step<false>(kbase, vbase, kt, l15, q, ps, qf0, qf1, o, rs);
    attn_step<true>(kbase, vbase, p, l15, q, ps, qf0, qf1, o, rs);
    attn_finalize(AO, b, h, p, l15, q, o, rs);
    // heavy-tile tail [17, 31-p] incl diag (empty when p==15)
#pragma unroll
    for (int md = 0; md < 4; ++md)
#pragma unroll
      for (int nq = 0; nq < 4; ++nq) o[md][nq] = f32x4{0.f, 0.f, 0.f, 0.f};
    rs[0] = rs[1] = rs[2] = rs[3] = 0.f;
    if (p < 15) {
      load_q(Qb, b, h, qt_h, l15, q, qf0, qf1);
      for (int kt = 17; kt < 31 - p; ++kt)
        attn_step<false>(kbase, vbase, kt, l15, q, ps, qf0, qf1, o, rs);
      attn_step<true>(kbase, vbase, 31 - p, l15, q, ps, qf0, qf1, o, rs);
    }
#pragma unroll
    for (int md = 0; md < 4; ++md)
#pragma unroll
      for (int nq = 0; nq < 4; ++nq)
        *(f32x4*)&Oc[((md * 4 + nq) * 64 + l) * 4] = o[md][nq];
#pragma unroll
    for (int nq = 0; nq < 4; ++nq) RSc[l * 4 + nq] = rs[nq];
    __syncthreads();  // release partial to wave0
  }
}

extern "C" void kernel_launch(void* const* d_in, const int* in_sizes, int n_in,
                              void* d_out, int out_size, void* d_ws, size_t ws_size,
                              hipStream_t stream) {
  (void)in_sizes; (void)n_in; (void)out_size; (void)ws_size;
  const int BS = 8192;  // B*S
  const float* x  = (const float*)d_in[0];
  const float* Wq = (const float*)d_in[1];
  const float* bq = (const float*)d_in[2];
  const float* Wk = (const float*)d_in[3];
  const float* bk = (const float*)d_in[4];
  const float* Wv = (const float*)d_in[5];
  const float* bv = (const float*)d_in[6];
  const float* Wo = (const float*)d_in[7];
  const float* bo = (const float*)d_in[8];
  float* out = (float*)d_out;

  bf16_t* p = (bf16_t*)d_ws;
  bf16_t* WqT  = p; p += 1024 * 1024;  // rows 0-1023 of fused Bt
  bf16_t* WkvT = p; p += 128 * 1024;   // rows 1024-1151 (contiguous after WqT)
  bf16_t* WoT  = p; p += 1024 * 1024;
  bf16_t* xb   = p; p += (size_t)BS * 1024;
  bf16_t* Qb   = p; p += (size_t)BS * 1024;
  bf16_t* KVb  = p; p += (size_t)BS * 128;   // cols 0-63 = K, 64-127 = V
  bf16_t* VtG  = p; p += (size_t)4 * 64 * 2048;
  float*  bqkv = (float*)p; p += 2304;       // 1152 f32
  bf16_t* AO  = xb;   // x dead after projections

  // 4 launches: prep, fused QKV gemm (+V^T side-write), attn, O gemm.
  prep<<<dim3(546 + 8192), 256, 0, stream>>>(x, Wq, Wk, Wv, Wo, bq, bk, bv,
                                             xb, WqT, WkvT, WoT, bqkv);

  gemm_qkv<<<dim3(BS / 64, 9), 256, 0, stream>>>(xb, WqT, bqkv, Qb, KVb, VtG, BS, 1024);

  mqa_attn9<<<dim3(1024), 128, 0, stream>>>(Qb, KVb, VtG, AO);

  gemm_nt_bias_f32<<<dim3(BS / 128, 8), 256, 0, stream>>>(AO, WoT, bo, out, BS, 1024, 1024);
}

// Round 14
// 227.684 us; speedup vs baseline: 1.0640x; 1.0640x over previous
//
#include <hip/hip_runtime.h>
#include <hip/hip_bf16.h>

typedef __bf16 bf16_t;
typedef __bf16 bf16x4 __attribute__((ext_vector_type(4)));
typedef __bf16 bf16x8 __attribute__((ext_vector_type(8)));
typedef float f32x4 __attribute__((ext_vector_type(4)));

#define AS1(p) ((const __attribute__((address_space(1))) void*)(p))
#define AS3(p) ((__attribute__((address_space(3))) void*)(p))

__device__ __forceinline__ f32x4 mfma16(bf16x8 a, bf16x8 b, f32x4 c) {
  return __builtin_amdgcn_mfma_f32_16x16x32_bf16(a, b, c, 0, 0, 0);
}

// ---- fused prep: x cast (8 f32/lane) + 4 weight transposes + bias build ----
__global__ void prep(const float* __restrict__ x, const float* __restrict__ Wq,
                     const float* __restrict__ Wk, const float* __restrict__ Wv,
                     const float* __restrict__ Wo, const float* __restrict__ bq,
                     const float* __restrict__ bk, const float* __restrict__ bv,
                     bf16_t* __restrict__ xb, bf16_t* __restrict__ WqT,
                     bf16_t* __restrict__ WkvT, bf16_t* __restrict__ WoT,
                     float* __restrict__ bqkv) {
  const int u = blockIdx.x;
  if (u >= 546) {  // x cast: 8192*1024 f32 -> bf16, 8/lane (4096 blocks)
    int i = ((u - 546) * 256 + threadIdx.x) * 8;
    float4 v0 = *(const float4*)(x + i);
    float4 v1 = *(const float4*)(x + i + 4);
    bf16x8 o = {(bf16_t)v0.x, (bf16_t)v0.y, (bf16_t)v0.z, (bf16_t)v0.w,
                (bf16_t)v1.x, (bf16_t)v1.y, (bf16_t)v1.z, (bf16_t)v1.w};
    *(bf16x8*)(xb + i) = o;
    return;
  }
  if (u == 544) {  // bq copy (1024 f32)
    int i = threadIdx.x * 4;
    *(float4*)(bqkv + i) = *(const float4*)(bq + i);
    return;
  }
  if (u == 545) {  // bk/bv pack
    if (threadIdx.x < 128)
      bqkv[1024 + threadIdx.x] =
          (threadIdx.x < 64) ? bk[threadIdx.x] : bv[threadIdx.x - 64];
    return;
  }
  const float* W; bf16_t* Wt; int N, bx, by;
  if (u < 256)      { W = Wq; Wt = WqT;              N = 1024; bx = u & 15;         by = u >> 4; }
  else if (u < 272) { W = Wk; Wt = WkvT;             N = 64;   bx = 0;              by = u - 256; }
  else if (u < 288) { W = Wv; Wt = WkvT + 64 * 1024; N = 64;   bx = 0;              by = u - 272; }
  else              { W = Wo; Wt = WoT;              N = 1024; bx = (u - 288) & 15; by = (u - 288) >> 4; }
  __shared__ float t[64][65];
  const int n0 = bx * 64, k0 = by * 64;
  const int tx = threadIdx.x & 63, ty = threadIdx.x >> 6;
#pragma unroll
  for (int i = 0; i < 16; ++i)
    t[ty * 16 + i][tx] = W[(size_t)(k0 + ty * 16 + i) * N + n0 + tx];
  __syncthreads();
#pragma unroll
  for (int i = 0; i < 16; ++i)
    Wt[(size_t)(n0 + ty * 16 + i) * 1024 + k0 + tx] = (bf16_t)t[tx][ty * 16 + i];
}

// Fused Q+KV projection, 128x128, BK=32, dbuf (round-11 proven best).
// GEMM probe ledger: BK=64 +6us, N-fastest +11us, BM=64 +15us, dbuf +-0.
// This shape is the local optimum for the 2-barrier structure.
__global__ __launch_bounds__(256, 2)
void gemm_qkv(const bf16_t* __restrict__ A, const bf16_t* __restrict__ Bt,
              const float* __restrict__ bias, bf16_t* __restrict__ Qb,
              bf16_t* __restrict__ KVb, bf16_t* __restrict__ VtG, int M, int K) {
  __shared__ __align__(16) bf16_t As[2][128 * 32];
  __shared__ __align__(16) bf16_t Bs[2][128 * 32];
  const int tid = threadIdx.x;
  const int w = tid >> 6, l = tid & 63;
  const int l15 = l & 15, q = l >> 4;
  const int m0 = blockIdx.x * 128, n0 = blockIdx.y * 128;
  const int mw = (w >> 1) * 64, nw = (w & 1) * 64;
  f32x4 acc[4][4] = {};
  const int kb = (l & 3) * 8;
  int rA[2], rB[2];
#pragma unroll
  for (int i = 0; i < 2; ++i) {
    int row = (i * 4 + w) * 16 + (l >> 2);
    rA[i] = m0 + row;
    rB[i] = n0 + row;  // N=1152 = 9*128 exactly
  }
  // prologue: stage tile 0 into buffer 0
#pragma unroll
  for (int i = 0; i < 2; ++i) {
    int sg = i * 4 + w;
    __builtin_amdgcn_global_load_lds(AS1(A + (size_t)rA[i] * K + kb),
                                     AS3(&As[0][0] + sg * 512), 16, 0, 0);
    __builtin_amdgcn_global_load_lds(AS1(Bt + (size_t)rB[i] * K + kb),
                                     AS3(&Bs[0][0] + sg * 512), 16, 0, 0);
  }
  const int NT = K / 32;
  for (int t = 0; t < NT; ++t) {
    __syncthreads();  // drains stage(t); releases the other buffer
    const int cur = t & 1;
    if (t + 1 < NT) {
      const int k0n = (t + 1) * 32;
#pragma unroll
      for (int i = 0; i < 2; ++i) {
        int sg = i * 4 + w;
        __builtin_amdgcn_global_load_lds(AS1(A + (size_t)rA[i] * K + k0n + kb),
                                         AS3(&As[cur ^ 1][0] + sg * 512), 16, 0, 0);
        __builtin_amdgcn_global_load_lds(AS1(Bt + (size_t)rB[i] * K + k0n + kb),
                                         AS3(&Bs[cur ^ 1][0] + sg * 512), 16, 0, 0);
      }
    }
    bf16x8 af[4], bfr[4];
#pragma unroll
    for (int mi = 0; mi < 4; ++mi)
      af[mi] = *(const bf16x8*)(&As[cur][0] + (mw + mi * 16 + l15) * 32 + q * 8);
#pragma unroll
    for (int ni = 0; ni < 4; ++ni)
      bfr[ni] = *(const bf16x8*)(&Bs[cur][0] + (nw + ni * 16 + l15) * 32 + q * 8);
#pragma unroll
    for (int mi = 0; mi < 4; ++mi)
#pragma unroll
      for (int ni = 0; ni < 4; ++ni)
        acc[mi][ni] = mfma16(af[mi], bfr[ni], acc[mi][ni]);
  }
#pragma unroll
  for (int ni = 0; ni < 4; ++ni) {
    int col = n0 + nw + ni * 16 + l15;
    float bv = bias[col];
#pragma unroll
    for (int mi = 0; mi < 4; ++mi)
#pragma unroll
      for (int r = 0; r < 4; ++r) {
        int row = m0 + mw + mi * 16 + q * 4 + r;
        bf16_t v = (bf16_t)(acc[mi][ni][r] + bv);
        if (col < 1024) {
          Qb[(size_t)row * 1024 + col] = v;
        } else {
          int c2 = col - 1024;
          KVb[(size_t)row * 128 + c2] = v;
          if (c2 >= 64)
            VtG[(size_t)((row >> 11) * 64 + (c2 - 64)) * 2048 + (row & 2047)] = v;
        }
      }
  }
}

// O-projection GEMM, 128x128, BK=32 + dbuf, M-fastest grid.
__global__ __launch_bounds__(256, 2)
void gemm_nt_bias_f32(const bf16_t* __restrict__ A, const bf16_t* __restrict__ Bt,
                      const float* __restrict__ bias, float* __restrict__ C,
                      int M, int N, int K) {
  __shared__ __align__(16) bf16_t As[2][128 * 32];
  __shared__ __align__(16) bf16_t Bs[2][128 * 32];
  const int tid = threadIdx.x;
  const int w = tid >> 6, l = tid & 63;
  const int l15 = l & 15, q = l >> 4;
  const int m0 = blockIdx.x * 128, n0 = blockIdx.y * 128;
  const int mw = (w >> 1) * 64, nw = (w & 1) * 64;
  f32x4 acc[4][4] = {};
  const int kb = (l & 3) * 8;
  int rA[2], rB[2];
#pragma unroll
  for (int i = 0; i < 2; ++i) {
    int row = (i * 4 + w) * 16 + (l >> 2);
    rA[i] = m0 + row;
    int rb = n0 + row; if (rb >= N) rb = N - 1;
    rB[i] = rb;
  }
#pragma unroll
  for (int i = 0; i < 2; ++i) {
    int sg = i * 4 + w;
    __builtin_amdgcn_global_load_lds(AS1(A + (size_t)rA[i] * K + kb),
                                     AS3(&As[0][0] + sg * 512), 16, 0, 0);
    __builtin_amdgcn_global_load_lds(AS1(Bt + (size_t)rB[i] * K + kb),
                                     AS3(&Bs[0][0] + sg * 512), 16, 0, 0);
  }
  const int NT = K / 32;
  for (int t = 0; t < NT; ++t) {
    __syncthreads();
    const int cur = t & 1;
    if (t + 1 < NT) {
      const int k0n = (t + 1) * 32;
#pragma unroll
      for (int i = 0; i < 2; ++i) {
        int sg = i * 4 + w;
        __builtin_amdgcn_global_load_lds(AS1(A + (size_t)rA[i] * K + k0n + kb),
                                         AS3(&As[cur ^ 1][0] + sg * 512), 16, 0, 0);
        __builtin_amdgcn_global_load_lds(AS1(Bt + (size_t)rB[i] * K + k0n + kb),
                                         AS3(&Bs[cur ^ 1][0] + sg * 512), 16, 0, 0);
      }
    }
    bf16x8 af[4], bfr[4];
#pragma unroll
    for (int mi = 0; mi < 4; ++mi)
      af[mi] = *(const bf16x8*)(&As[cur][0] + (mw + mi * 16 + l15) * 32 + q * 8);
#pragma unroll
    for (int ni = 0; ni < 4; ++ni)
      bfr[ni] = *(const bf16x8*)(&Bs[cur][0] + (nw + ni * 16 + l15) * 32 + q * 8);
#pragma unroll
    for (int mi = 0; mi < 4; ++mi)
#pragma unroll
      for (int ni = 0; ni < 4; ++ni)
        acc[mi][ni] = mfma16(af[mi], bfr[ni], acc[mi][ni]);
  }
#pragma unroll
  for (int ni = 0; ni < 4; ++ni) {
    int col = n0 + nw + ni * 16 + l15;
    if (col >= N) continue;
    float bv = bias[col];
#pragma unroll
    for (int mi = 0; mi < 4; ++mi)
#pragma unroll
      for (int r = 0; r < 4; ++r) {
        int row = m0 + mw + mi * 16 + q * 4 + r;
        C[(size_t)row * N + col] = acc[mi][ni][r] + bv;
      }
  }
}

// ---- MQA flash v9 attn (proven 77.3us, VGPR 112, no spill) -- verbatim ----
__device__ __forceinline__ void load_q(const bf16_t* __restrict__ Qb, int b, int h,
                                       int qt, int l15, int q,
                                       bf16x8 (&qf0)[4], bf16x8 (&qf1)[4]) {
#pragma unroll
  for (int nq = 0; nq < 4; ++nq) {
    const bf16_t* qp = Qb + (size_t)(b * 2048 + qt * 64 + nq * 16 + l15) * 1024 + h * 64 + q * 8;
    qf0[nq] = *(const bf16x8*)qp;
    qf1[nq] = *(const bf16x8*)(qp + 32);
  }
}

template <bool DIAG>
__device__ __forceinline__ void attn_step(
    const bf16_t* __restrict__ kbase, const bf16_t* __restrict__ vbase, int kt,
    int l15, int q, bf16_t* __restrict__ ps,
    const bf16x8 (&qf0)[4], const bf16x8 (&qf1)[4],
    f32x4 (&o)[4][4], float (&rs)[4]) {
  const float c1 = 0.18033688f;  // log2(e)/8
  const bf16_t* kb = kbase + (size_t)kt * 64 * 128;  // K: cols 0-63 of KVb rows
  bf16x8 ka0[4], ka1[4];
#pragma unroll
  for (int mk = 0; mk < 4; ++mk) {
    const bf16_t* kr = kb + (mk * 16 + l15) * 128;
    ka0[mk] = *(const bf16x8*)(kr + q * 8);
    ka1[mk] = *(const bf16x8*)(kr + 32 + q * 8);
  }
  bf16x8 va0[4], va1[4];
#pragma unroll
  for (int md = 0; md < 4; ++md) {
    const bf16_t* vr = vbase + (size_t)(md * 16 + l15) * 2048 + kt * 64;
    va0[md] = *(const bf16x8*)(vr + q * 8);
    va1[md] = *(const bf16x8*)(vr + 32 + q * 8);
  }
  // S^T = K*Q^T in two mk-halves (bounds live s-registers)
#pragma unroll
  for (int mh = 0; mh < 2; ++mh) {
    f32x4 s2[2][4];
    __builtin_amdgcn_s_setprio(1);
#pragma unroll
    for (int mk2 = 0; mk2 < 2; ++mk2)
#pragma unroll
      for (int nq = 0; nq < 4; ++nq) {
        f32x4 t = {0.f, 0.f, 0.f, 0.f};
        t = mfma16(ka0[mh * 2 + mk2], qf0[nq], t);
        t = mfma16(ka1[mh * 2 + mk2], qf1[nq], t);
        s2[mk2][nq] = t;
      }
    __builtin_amdgcn_s_setprio(0);
#pragma unroll
    for (int nq = 0; nq < 4; ++nq)
#pragma unroll
      for (int mk2 = 0; mk2 < 2; ++mk2) {
        const int mk = mh * 2 + mk2;
        bf16x4 pk;
#pragma unroll
        for (int r = 0; r < 4; ++r) {
          float pv = __builtin_amdgcn_exp2f(s2[mk2][nq][r] * c1 - 16.0f);
          if (DIAG && (mk * 16 + q * 4 + r) > (nq * 16 + l15)) pv = 0.f;
          rs[nq] += pv;
          pk[r] = (bf16_t)pv;
        }
        *(bf16x4*)(ps + nq * 1152 + l15 * 72 + mk * 16 + q * 4) = pk;
      }
  }
  // O^T += V^T * P
#pragma unroll
  for (int nq = 0; nq < 4; ++nq) {
    bf16x8 pb0 = *(const bf16x8*)(ps + nq * 1152 + l15 * 72 + q * 8);
    bf16x8 pb1 = *(const bf16x8*)(ps + nq * 1152 + l15 * 72 + 32 + q * 8);
    __builtin_amdgcn_s_setprio(1);
#pragma unroll
    for (int md = 0; md < 4; ++md) {
      o[md][nq] = mfma16(va0[md], pb0, o[md][nq]);
      o[md][nq] = mfma16(va1[md], pb1, o[md][nq]);
    }
    __builtin_amdgcn_s_setprio(0);
  }
}

__device__ __forceinline__ void attn_finalize(bf16_t* __restrict__ AO, int b, int h,
                                              int qt, int l15, int q,
                                              f32x4 (&o)[4][4], float (&rs)[4]) {
#pragma unroll
  for (int nq = 0; nq < 4; ++nq) {
    rs[nq] += __shfl_xor(rs[nq], 16);
    rs[nq] += __shfl_xor(rs[nq], 32);
  }
  float inv[4];
#pragma unroll
  for (int nq = 0; nq < 4; ++nq) inv[nq] = 1.f / rs[nq];
#pragma unroll
  for (int md = 0; md < 4; ++md)
#pragma unroll
    for (int nq = 0; nq < 4; ++nq) {
      bf16x4 ov = {(bf16_t)(o[md][nq][0] * inv[nq]), (bf16_t)(o[md][nq][1] * inv[nq]),
                   (bf16_t)(o[md][nq][2] * inv[nq]), (bf16_t)(o[md][nq][3] * inv[nq])};
      *(bf16x4*)(AO + (size_t)(b * 2048 + qt * 64 + nq * 16 + l15) * 1024 +
                 h * 64 + md * 16 + q * 4) = ov;
    }
}

__global__ __launch_bounds__(128, 2)
void mqa_attn9(const bf16_t* __restrict__ Qb, const bf16_t* __restrict__ KVb,
               const bf16_t* __restrict__ VtG, bf16_t* __restrict__ AO) {
  __shared__ __align__(16) bf16_t Ps[2][4][16 * 72];  // 18 KB
  __shared__ __align__(16) float Oc[4096];            // 16 KB combine buffer
  __shared__ float RSc[256];                          // 1 KB
  const int u = blockIdx.x;
  const int b = u & 3;                 // one batch per XCD L2
  const int h = (u >> 2) & 15;
  const int p = (u >> 6) & 15;         // pair id; qt_h = 31-p, qt_l = p
  const int w = threadIdx.x >> 6, l = threadIdx.x & 63;
  const int l15 = l & 15, q = l >> 4;
  const int qt_h = 31 - p;
  bf16_t* ps = &Ps[w][0][0];
  const bf16_t* kbase = KVb + (size_t)b * 2048 * 128;
  const bf16_t* vbase = VtG + (size_t)b * 64 * 2048;

  bf16x8 qf0[4], qf1[4];
  f32x4 o[4][4] = {};
  float rs[4] = {0.f, 0.f, 0.f, 0.f};

  if (w == 0) {
    // first 17 steps of the heavy tile (diag included only when p==15)
    load_q(Qb, b, h, qt_h, l15, q, qf0, qf1);
    const int e = (p == 15) ? 16 : 17;
    for (int kt = 0; kt < e; ++kt)
      attn_step<false>(kbase, vbase, kt, l15, q, ps, qf0, qf1, o, rs);
    if (p == 15)
      attn_step<true>(kbase, vbase, 16, l15, q, ps, qf0, qf1, o, rs);
    __syncthreads();  // wave1's partial is in Oc/RSc
#pragma unroll
    for (int md = 0; md < 4; ++md)
#pragma unroll
      for (int nq = 0; nq < 4; ++nq)
        o[md][nq] += *(const f32x4*)&Oc[((md * 4 + nq) * 64 + l) * 4];
#pragma unroll
    for (int nq = 0; nq < 4; ++nq) rs[nq] += RSc[l * 4 + nq];
    attn_finalize(AO, b, h, qt_h, l15, q, o, rs);
  } else {
    // light tile complete (p steps + diag), written directly
    load_q(Qb, b, h, p, l15, q, qf0, qf1);
    for (int kt = 0; kt < p; ++kt)
      attn_step<false>(kbase, vbase, kt, l15, q, ps, qf0, qf1, o, rs);
    attn_step<true>(kbase, vbase, p, l15, q, ps, qf0, qf1, o, rs);
    attn_finalize(AO, b, h, p, l15, q, o, rs);
    // heavy-tile tail [17, 31-p] incl diag (empty when p==15)
#pragma unroll
    for (int md = 0; md < 4; ++md)
#pragma unroll
      for (int nq = 0; nq < 4; ++nq) o[md][nq] = f32x4{0.f, 0.f, 0.f, 0.f};
    rs[0] = rs[1] = rs[2] = rs[3] = 0.f;
    if (p < 15) {
      load_q(Qb, b, h, qt_h, l15, q, qf0, qf1);
      for (int kt = 17; kt < 31 - p; ++kt)
        attn_step<false>(kbase, vbase, kt, l15, q, ps, qf0, qf1, o, rs);
      attn_step<true>(kbase, vbase, 31 - p, l15, q, ps, qf0, qf1, o, rs);
    }
#pragma unroll
    for (int md = 0; md < 4; ++md)
#pragma unroll
      for (int nq = 0; nq < 4; ++nq)
        *(f32x4*)&Oc[((md * 4 + nq) * 64 + l) * 4] = o[md][nq];
#pragma unroll
    for (int nq = 0; nq < 4; ++nq) RSc[l * 4 + nq] = rs[nq];
    __syncthreads();  // release partial to wave0
  }
}

extern "C" void kernel_launch(void* const* d_in, const int* in_sizes, int n_in,
                              void* d_out, int out_size, void* d_ws, size_t ws_size,
                              hipStream_t stream) {
  (void)in_sizes; (void)n_in; (void)out_size; (void)ws_size;
  const int BS = 8192;  // B*S
  const float* x  = (const float*)d_in[0];
  const float* Wq = (const float*)d_in[1];
  const float* bq = (const float*)d_in[2];
  const float* Wk = (const float*)d_in[3];
  const float* bk = (const float*)d_in[4];
  const float* Wv = (const float*)d_in[5];
  const float* bv = (const float*)d_in[6];
  const float* Wo = (const float*)d_in[7];
  const float* bo = (const float*)d_in[8];
  float* out = (float*)d_out;

  bf16_t* p = (bf16_t*)d_ws;
  bf16_t* WqT  = p; p += 1024 * 1024;  // rows 0-1023 of fused Bt
  bf16_t* WkvT = p; p += 128 * 1024;   // rows 1024-1151 (contiguous after WqT)
  bf16_t* WoT  = p; p += 1024 * 1024;
  bf16_t* xb   = p; p += (size_t)BS * 1024;
  bf16_t* Qb   = p; p += (size_t)BS * 1024;
  bf16_t* KVb  = p; p += (size_t)BS * 128;   // cols 0-63 = K, 64-127 = V
  bf16_t* VtG  = p; p += (size_t)4 * 64 * 2048;
  float*  bqkv = (float*)p; p += 2304;       // 1152 f32
  bf16_t* AO  = xb;   // x dead after projections

  // 4 launches: prep, fused QKV gemm (+V^T side-write), attn, O gemm.
  prep<<<dim3(546 + 4096), 256, 0, stream>>>(x, Wq, Wk, Wv, Wo, bq, bk, bv,
                                             xb, WqT, WkvT, WoT, bqkv);

  gemm_qkv<<<dim3(BS / 128, 9), 256, 0, stream>>>(xb, WqT, bqkv, Qb, KVb, VtG, BS, 1024);

  mqa_attn9<<<dim3(1024), 128, 0, stream>>>(Qb, KVb, VtG, AO);

  gemm_nt_bias_f32<<<dim3(BS / 128, 8), 256, 0, stream>>>(AO, WoT, bo, out, BS, 1024, 1024);
}